// Round 2
// baseline (2010.764 us; speedup 1.0000x reference)
//
#include <hip/hip_runtime.h>
#include <cstdint>
#include <cstddef>

// ---------------- types & helpers ----------------
typedef unsigned short u16;
typedef __bf16 bf16x8 __attribute__((ext_vector_type(8)));
typedef u16    u16x8  __attribute__((ext_vector_type(8)));
typedef float  f32x4  __attribute__((ext_vector_type(4)));

static __device__ __forceinline__ u16 f2bf(float f) {
  uint32_t u = __builtin_bit_cast(uint32_t, f);
  u += 0x7FFFu + ((u >> 16) & 1u);           // round-to-nearest-even
  return (u16)(u >> 16);
}
static __device__ __forceinline__ float bf2f(u16 h) {
  return __builtin_bit_cast(float, (uint32_t)h << 16);
}
static __device__ __forceinline__ bf16x8 as_bf(u16x8 v) {
  union { u16x8 u; bf16x8 b; } x; x.u = v; return x.b;
}

#define GLD_LDS(src, dst)                                                      \
  __builtin_amdgcn_global_load_lds(                                            \
      (const __attribute__((address_space(1))) void*)(const void*)(src),       \
      (__attribute__((address_space(3))) void*)(void*)(dst), 16, 0, 0)

// problem constants
#define T_TOK 16384
#define DDIM  1024
#define EEXP  8
#define HDIM  4096
#define BM256 256
#define MAXTILES 136         // sum ceil(c_e/256) <= 135
#define MAXSLOTS 34816       // 136 * 256

// ---------------- transpose + fp32->bf16 cast (vectorized) -----------------
// in: per-expert R x C (row-major f32), out: per-expert C x R (row-major bf16)
__global__ __launch_bounds__(256) void transpose_cast64(
    const float* __restrict__ in, u16* __restrict__ out, int R, int C) {
  __shared__ float t[64][65];
  int e = blockIdx.z;
  const float* src = in + (size_t)e * R * C;
  u16* dst = out + (size_t)e * R * C;
  int r0 = blockIdx.y << 6, c0 = blockIdx.x << 6;
  int tr = threadIdx.x >> 4;          // 0..15
  int tc = (threadIdx.x & 15) << 2;   // 0..60
#pragma unroll
  for (int i = 0; i < 4; i++) {
    const float4 v = *(const float4*)(src + (size_t)(r0 + tr + i * 16) * C + c0 + tc);
    t[tr + i * 16][tc + 0] = v.x;
    t[tr + i * 16][tc + 1] = v.y;
    t[tr + i * 16][tc + 2] = v.z;
    t[tr + i * 16][tc + 3] = v.w;
  }
  __syncthreads();
  int oc = threadIdx.x >> 3;          // 0..31
  int rr = (threadIdx.x & 7) << 3;    // 0..56
#pragma unroll
  for (int i = 0; i < 2; i++) {
    int c = oc + (i << 5);
    u16x8 o;
#pragma unroll
    for (int j = 0; j < 8; j++) o[j] = f2bf(t[rr + j][c]);
    *(u16x8*)(dst + (size_t)(c0 + c) * R + r0 + rr) = o;
  }
}

// ---------------- router: fp32 logits, top-2, softmax; fused x->bf16 -------
__global__ __launch_bounds__(256) void router_kernel(
    const float* __restrict__ x, const float* __restrict__ Wg,
    const float* __restrict__ bg, u16* __restrict__ xbf,
    int2* __restrict__ tok_e, float2* __restrict__ tok_g,
    int* __restrict__ counts) {
  int w = threadIdx.x >> 6, lane = threadIdx.x & 63;
  int t = blockIdx.x * 4 + w;
  const float* xr = x + (size_t)t * DDIM;
  float acc[EEXP] = {0.f, 0.f, 0.f, 0.f, 0.f, 0.f, 0.f, 0.f};
#pragma unroll
  for (int j = 0; j < DDIM / 64; j++) {
    int d = j * 64 + lane;
    float xv = xr[d];
    xbf[(size_t)t * DDIM + d] = f2bf(xv);
    const float4* wv = (const float4*)(Wg + (size_t)d * EEXP);
    float4 wa = wv[0], wb = wv[1];
    acc[0] += xv * wa.x; acc[1] += xv * wa.y;
    acc[2] += xv * wa.z; acc[3] += xv * wa.w;
    acc[4] += xv * wb.x; acc[5] += xv * wb.y;
    acc[6] += xv * wb.z; acc[7] += xv * wb.w;
  }
#pragma unroll
  for (int e = 0; e < EEXP; e++) {
    float v = acc[e];
    for (int s = 32; s; s >>= 1) v += __shfl_xor(v, s);
    acc[e] = v + bg[e];
  }
  int e0 = 0; float v0 = acc[0];
#pragma unroll
  for (int e = 1; e < EEXP; e++) if (acc[e] > v0) { v0 = acc[e]; e0 = e; }
  int e1 = -1; float v1 = -3.402823466e38f;
#pragma unroll
  for (int e = 0; e < EEXP; e++)
    if (e != e0 && acc[e] > v1) { v1 = acc[e]; e1 = e; }
  float p0 = 1.f / (1.f + expf(v1 - v0));
  float p1 = 1.f - p0;
  if (lane == 0) {
    atomicAdd(&counts[e0], 1);
    atomicAdd(&counts[e1], 1);
    tok_e[t] = make_int2(e0, e1);
    tok_g[t] = make_float2(p0, p1);
  }
}

// ---------------- scan: per-expert bases (256-padded) + tile table ---------
__global__ void scan_kernel(const int* __restrict__ counts,
                            int* __restrict__ expBase,
                            int* __restrict__ tileExpert,
                            int* __restrict__ tileRow0,
                            int* __restrict__ nTiles) {
  if (threadIdx.x != 0 || blockIdx.x != 0) return;
  int base = 0, nt = 0;
  for (int e = 0; e < EEXP; e++) {
    expBase[e] = base;
    int c = counts[e];
    int tiles = (c + BM256 - 1) >> 8;
    for (int i = 0; i < tiles; i++) {
      tileExpert[nt] = e;
      tileRow0[nt] = base + (i << 8);
      nt++;
    }
    base += tiles << 8;
  }
  *nTiles = nt;
}

// ---------------- scatter: slot assignment + per-slot gate -----------------
__global__ __launch_bounds__(256) void scatter_kernel(
    const int2* __restrict__ tok_e, int* __restrict__ cursor,
    const int* __restrict__ expBase, int* __restrict__ rowmap,
    float* __restrict__ gateOf, const float2* __restrict__ tok_g) {
  int t = blockIdx.x * 256 + threadIdx.x;
  int2 e = tok_e[t];
  float2 g = tok_g[t];
  int s0 = expBase[e.x] + atomicAdd(&cursor[e.x], 1);
  int s1 = expBase[e.y] + atomicAdd(&cursor[e.y], 1);
  rowmap[s0] = t;
  rowmap[s1] = t;
  gateOf[s0] = g.x;
  gateOf[s1] = g.y;
}

// ---------------- grouped GEMM, 256x256 tile, 4-phase/K-tile schedule ------
// T2: chunk-XOR LDS swizzle (linear gload_lds dest + inverse-swizzled global
//     source + swizzled ds_read)  [rule #21]
// T3+T4: raw s_barrier, issue-early prefetch, single counted wait per K-tile
// T5: setprio around each 16-MFMA cluster
template <bool RELU_STORE, bool GATHER, bool ATOMIC_OUT>
__global__ __launch_bounds__(512) void moe_gemm256(
    const u16* __restrict__ A,      // [rows][K] bf16
    const u16* __restrict__ Bt,     // [E][N][K] bf16
    const float* __restrict__ bias, // [E][N]
    u16* __restrict__ Cbf,          // GEMM1 out: [slots][N] bf16
    float* __restrict__ Cout,       // GEMM2 out: [T][DDIM] f32 (atomic)
    const float* __restrict__ gateOf, const int* __restrict__ rowmap,
    const int* __restrict__ tileExpert, const int* __restrict__ tileRow0,
    const int* __restrict__ nTiles, int N, int K) {
  __shared__ __align__(16) u16 As[2][256 * 64];
  __shared__ __align__(16) u16 Bs[2][256 * 64];
  int ntl = N >> 8;
  int nwg = (int)gridDim.x;
  int bid = (int)blockIdx.x;
  int swzb = (bid & 7) * (nwg >> 3) + (bid >> 3);   // bijective XCD swizzle
  int mtile = swzb / ntl, ntile = swzb - mtile * ntl;
  if (mtile >= *nTiles) return;
  int e = tileExpert[mtile];
  int row0 = tileRow0[mtile];
  int ncol0 = ntile << 8;
  const u16* Bm = Bt + (size_t)e * N * K;
  const float* bb = bias + (size_t)e * N;

  int tid = threadIdx.x;
  int wv = tid >> 6, lane = tid & 63;
  int wr = wv >> 2, wc = wv & 3;
  int rlo = lane & 15, hi = lane >> 4;

  // staging sources: 16B chunk cc = tid + j*512 of a [256 row][64 k] tile.
  // LDS chunk (row, kc) holds global chunk (row, kc ^ (row&7))  [T2 inverse]
  int srow = tid >> 3;                      // 0..63 (+ j*64)
  int gkc = (tid & 7) ^ (srow & 7);
  const u16* asrc[4]; const u16* bsrc[4];
#pragma unroll
  for (int j = 0; j < 4; j++) {
    int row = j * 64 + srow;
    int ar = GATHER ? rowmap[row0 + row] : (row0 + row);
    asrc[j] = A + (size_t)ar * K + gkc * 8;
    bsrc[j] = Bm + (size_t)(ncol0 + row) * K + gkc * 8;
  }

  f32x4 acc[8][4] = {};
  int nkt = K >> 6;

  // prologue: stage tile 0 into buffer 0 (8 x global_load_lds, 16B/lane)
#pragma unroll
  for (int j = 0; j < 4; j++) GLD_LDS(asrc[j], &As[0][j * 4096 + wv * 512]);
#pragma unroll
  for (int j = 0; j < 4; j++) GLD_LDS(bsrc[j], &Bs[0][j * 4096 + wv * 512]);

  // swizzled read offsets (elems): chunk c = hi (+4 for kk=32), XOR rlo&7
  int swA0 = ((hi + 0) ^ (rlo & 7)) * 8;
  int swA4 = ((hi + 4) ^ (rlo & 7)) * 8;

  for (int kt = 0; kt < nkt; ++kt) {
    const u16* as = As[kt & 1];
    const u16* bs = Bs[kt & 1];
    u16* an = As[(kt & 1) ^ 1];
    u16* bn = Bs[(kt & 1) ^ 1];
    int sk = (kt + 1) << 6;
    bool pf = (kt + 1 < nkt);                // block-uniform

    // rendezvous: own DMA done + everyone past previous tile's reads.
    asm volatile("s_waitcnt vmcnt(0)" ::: "memory");
    __builtin_amdgcn_s_barrier();
    __builtin_amdgcn_sched_barrier(0);

    u16x8 af[4][2], b0[2][2], b1[2][2];
    // ---- phase 0: prefetch A(t+1); read A-quad0 + B-half0; MFMA q(0,0) ----
    if (pf) {
#pragma unroll
      for (int j = 0; j < 4; j++) GLD_LDS(asrc[j] + sk, &an[j * 4096 + wv * 512]);
    }
#pragma unroll
    for (int m = 0; m < 4; m++) {
      int rb = (wr * 128 + m * 16 + rlo) * 64;
      af[m][0] = *(const u16x8*)(as + rb + swA0);
      af[m][1] = *(const u16x8*)(as + rb + swA4);
    }
#pragma unroll
    for (int n = 0; n < 2; n++) {
      int rb = (wc * 64 + n * 16 + rlo) * 64;
      b0[n][0] = *(const u16x8*)(bs + rb + swA0);
      b0[n][1] = *(const u16x8*)(bs + rb + swA4);
    }
    __builtin_amdgcn_s_setprio(1);
#pragma unroll
    for (int m = 0; m < 4; m++)
#pragma unroll
      for (int n = 0; n < 2; n++) {
        acc[m][n] = __builtin_amdgcn_mfma_f32_16x16x32_bf16(as_bf(af[m][0]), as_bf(b0[n][0]), acc[m][n], 0, 0, 0);
        acc[m][n] = __builtin_amdgcn_mfma_f32_16x16x32_bf16(as_bf(af[m][1]), as_bf(b0[n][1]), acc[m][n], 0, 0, 0);
      }
    __builtin_amdgcn_s_setprio(0);
    __builtin_amdgcn_s_barrier();

    // ---- phase 1: prefetch B(t+1); read B-half1; MFMA q(0,1) ----
    if (pf) {
#pragma unroll
      for (int j = 0; j < 4; j++) GLD_LDS(bsrc[j] + sk, &bn[j * 4096 + wv * 512]);
    }
#pragma unroll
    for (int n = 0; n < 2; n++) {
      int rb = (wc * 64 + (n + 2) * 16 + rlo) * 64;
      b1[n][0] = *(const u16x8*)(bs + rb + swA0);
      b1[n][1] = *(const u16x8*)(bs + rb + swA4);
    }
    __builtin_amdgcn_s_setprio(1);
#pragma unroll
    for (int m = 0; m < 4; m++)
#pragma unroll
      for (int n = 0; n < 2; n++) {
        acc[m][n + 2] = __builtin_amdgcn_mfma_f32_16x16x32_bf16(as_bf(af[m][0]), as_bf(b1[n][0]), acc[m][n + 2], 0, 0, 0);
        acc[m][n + 2] = __builtin_amdgcn_mfma_f32_16x16x32_bf16(as_bf(af[m][1]), as_bf(b1[n][1]), acc[m][n + 2], 0, 0, 0);
      }
    __builtin_amdgcn_s_setprio(0);
    __builtin_amdgcn_s_barrier();

    // ---- phase 2: read A-quad1; MFMA q(1,1) (reuse b1) ----
#pragma unroll
    for (int m = 0; m < 4; m++) {
      int rb = (wr * 128 + (m + 4) * 16 + rlo) * 64;
      af[m][0] = *(const u16x8*)(as + rb + swA0);
      af[m][1] = *(const u16x8*)(as + rb + swA4);
    }
    __builtin_amdgcn_s_setprio(1);
#pragma unroll
    for (int m = 0; m < 4; m++)
#pragma unroll
      for (int n = 0; n < 2; n++) {
        acc[m + 4][n + 2] = __builtin_amdgcn_mfma_f32_16x16x32_bf16(as_bf(af[m][0]), as_bf(b1[n][0]), acc[m + 4][n + 2], 0, 0, 0);
        acc[m + 4][n + 2] = __builtin_amdgcn_mfma_f32_16x16x32_bf16(as_bf(af[m][1]), as_bf(b1[n][1]), acc[m + 4][n + 2], 0, 0, 0);
      }
    __builtin_amdgcn_s_setprio(0);
    __builtin_amdgcn_s_barrier();

    // ---- phase 3: MFMA q(1,0) (reuse af quad1, b0) ----
    __builtin_amdgcn_s_setprio(1);
#pragma unroll
    for (int m = 0; m < 4; m++)
#pragma unroll
      for (int n = 0; n < 2; n++) {
        acc[m + 4][n] = __builtin_amdgcn_mfma_f32_16x16x32_bf16(as_bf(af[m][0]), as_bf(b0[n][0]), acc[m + 4][n], 0, 0, 0);
        acc[m + 4][n] = __builtin_amdgcn_mfma_f32_16x16x32_bf16(as_bf(af[m][1]), as_bf(b0[n][1]), acc[m + 4][n], 0, 0, 0);
      }
    __builtin_amdgcn_s_setprio(0);
    // no trailing barrier: next tile's rendezvous covers it
  }

  asm volatile("s_waitcnt vmcnt(0)" ::: "memory");  // safety drain
  int r4 = hi * 4;
  if (!ATOMIC_OUT) {
    // GEMM1 epilogue: bias + relu, bf16 store
#pragma unroll
    for (int m = 0; m < 8; m++) {
      int rb = row0 + wr * 128 + m * 16 + r4;
#pragma unroll
      for (int n = 0; n < 4; n++) {
        int col = ncol0 + wc * 64 + n * 16 + rlo;
        float bv = bb[col];
#pragma unroll
        for (int j = 0; j < 4; j++) {
          float v = acc[m][n][j] + bv;
          if (RELU_STORE) v = fmaxf(v, 0.f);
          Cbf[(size_t)(rb + j) * N + col] = f2bf(v);
        }
      }
    }
  } else {
    // GEMM2 epilogue: fused combine — out[tok] += gate * (acc + bias)
#pragma unroll
    for (int m = 0; m < 8; m++) {
      int rb = row0 + wr * 128 + m * 16 + r4;
#pragma unroll
      for (int j = 0; j < 4; j++) {
        int slot = rb + j;
        float g = gateOf[slot];
        if (g != 0.f) {                      // pad slots have g == 0
          int t = rowmap[slot];
          float* op = Cout + (size_t)t * DDIM;
#pragma unroll
          for (int n = 0; n < 4; n++) {
            int col = ncol0 + wc * 64 + n * 16 + rlo;
            atomicAdd(op + col, g * (acc[m][n][j] + bb[col]));
          }
        }
      }
    }
  }
}

// ---------------- launch ----------------
extern "C" void kernel_launch(void* const* d_in, const int* in_sizes, int n_in,
                              void* d_out, int out_size, void* d_ws,
                              size_t ws_size, hipStream_t stream) {
  (void)in_sizes; (void)n_in; (void)ws_size;
  const float* x  = (const float*)d_in[0];
  const float* Wg = (const float*)d_in[1];
  const float* bg = (const float*)d_in[2];
  const float* W1 = (const float*)d_in[3];
  const float* b1 = (const float*)d_in[4];
  const float* W2 = (const float*)d_in[5];
  const float* b2 = (const float*)d_in[6];
  float* out = (float*)d_out;

  char* ws = (char*)d_ws;
  size_t o = 0;
  u16* W1T = (u16*)(ws + o); o += (size_t)EEXP * DDIM * HDIM * 2;   // 67.1 MB
  u16* W2T = (u16*)(ws + o); o += (size_t)EEXP * HDIM * DDIM * 2;   // 67.1 MB
  u16* xbf = (u16*)(ws + o); o += (size_t)T_TOK * DDIM * 2;         // 33.6 MB
  u16* Hbuf = (u16*)(ws + o); o += (size_t)MAXSLOTS * HDIM * 2;     // 285.2 MB
  int* rowmap = (int*)(ws + o); o += (size_t)MAXSLOTS * 4;
  float* gateOf = (float*)(ws + o); o += (size_t)MAXSLOTS * 4;
  int2* tok_e = (int2*)(ws + o); o += (size_t)T_TOK * 8;
  float2* tok_g = (float2*)(ws + o); o += (size_t)T_TOK * 8;
  int* counts = (int*)(ws + o); o += 8 * 4;
  int* cursor = (int*)(ws + o); o += 8 * 4;
  int* expBase = (int*)(ws + o); o += 8 * 4;
  int* nTiles = (int*)(ws + o); o += 8 * 4;
  int* tileExpert = (int*)(ws + o); o += MAXTILES * 4;
  int* tileRow0 = (int*)(ws + o); o += MAXTILES * 4;

  hipMemsetAsync(counts, 0, 16 * 4, stream);          // counts + cursor
  hipMemsetAsync(rowmap, 0, (size_t)MAXSLOTS * 4, stream);
  hipMemsetAsync(gateOf, 0, (size_t)MAXSLOTS * 4, stream);
  hipMemsetAsync(out, 0, (size_t)out_size * 4, stream);

  // W1 (E,D,H) -> W1T (E,H,D);  W2 (E,H,D) -> W2T (E,D,H)
  transpose_cast64<<<dim3(HDIM / 64, DDIM / 64, EEXP), 256, 0, stream>>>(W1, W1T, DDIM, HDIM);
  transpose_cast64<<<dim3(DDIM / 64, HDIM / 64, EEXP), 256, 0, stream>>>(W2, W2T, HDIM, DDIM);

  router_kernel<<<T_TOK / 4, 256, 0, stream>>>(x, Wg, bg, xbf, tok_e, tok_g, counts);
  scan_kernel<<<1, 64, 0, stream>>>(counts, expBase, tileExpert, tileRow0, nTiles);
  scatter_kernel<<<T_TOK / 256, 256, 0, stream>>>(tok_e, cursor, expBase, rowmap, gateOf, tok_g);

  // GEMM1: H = relu(x[rowmap] @ W1[e] + b1[e])   N=4096, K=1024  (2176 blocks)
  moe_gemm256<true, true, false><<<MAXTILES * (HDIM / 256), 512, 0, stream>>>(
      xbf, W1T, b1, Hbuf, nullptr, nullptr, rowmap, tileExpert, tileRow0, nTiles, HDIM, DDIM);
  // GEMM2: out[tok] += g * (H @ W2[e] + b2[e])   N=1024, K=4096  (544 blocks)
  moe_gemm256<false, false, true><<<MAXTILES * (DDIM / 256), 512, 0, stream>>>(
      Hbuf, W2T, b2, nullptr, out, gateOf, rowmap, tileExpert, tileRow0, nTiles, DDIM, HDIM);
}

// Round 5
// 1655.909 us; speedup vs baseline: 1.2143x; 1.2143x over previous
//
#include <hip/hip_runtime.h>
#include <cstdint>
#include <cstddef>

// ---------------- types & helpers ----------------
typedef unsigned short u16;
typedef __bf16 bf16x8 __attribute__((ext_vector_type(8)));
typedef u16    u16x8  __attribute__((ext_vector_type(8)));
typedef float  f32x4  __attribute__((ext_vector_type(4)));

static __device__ __forceinline__ u16 f2bf(float f) {
  uint32_t u = __builtin_bit_cast(uint32_t, f);
  u += 0x7FFFu + ((u >> 16) & 1u);           // round-to-nearest-even
  return (u16)(u >> 16);
}
static __device__ __forceinline__ float bf2f(u16 h) {
  return __builtin_bit_cast(float, (uint32_t)h << 16);
}
static __device__ __forceinline__ bf16x8 as_bf(u16x8 v) {
  union { u16x8 u; bf16x8 b; } x; x.u = v; return x.b;
}
static __device__ __forceinline__ f32x4 mf(u16x8 a, u16x8 b, f32x4 c) {
  return __builtin_amdgcn_mfma_f32_16x16x32_bf16(as_bf(a), as_bf(b), c, 0, 0, 0);
}

#define GLD_LDS(src, dst)                                                      \
  __builtin_amdgcn_global_load_lds(                                            \
      (const __attribute__((address_space(1))) void*)(const void*)(src),       \
      (__attribute__((address_space(3))) void*)(void*)(dst), 16, 0, 0)

#define VMC6 asm volatile("s_waitcnt vmcnt(6)" ::: "memory")
#define VMC4 asm volatile("s_waitcnt vmcnt(4)" ::: "memory")
#define VMC2 asm volatile("s_waitcnt vmcnt(2)" ::: "memory")
#define VMC0 asm volatile("s_waitcnt vmcnt(0)" ::: "memory")
#define LGK0 do { asm volatile("s_waitcnt lgkmcnt(0)" ::: "memory"); \
                  __builtin_amdgcn_sched_barrier(0); } while (0)
#define BARR __builtin_amdgcn_s_barrier()

// problem constants
#define T_TOK 16384
#define DDIM  1024
#define EEXP  8
#define HDIM  4096
#define BM256 256
#define MAXTILES 136         // sum ceil(c_e/256) <= 135
#define MAXSLOTS 34816       // 136 * 256

// ---------------- transpose + fp32->bf16 cast (vectorized) -----------------
__global__ __launch_bounds__(256) void transpose_cast64(
    const float* __restrict__ in, u16* __restrict__ out, int R, int C) {
  __shared__ float t[64][65];
  int e = blockIdx.z;
  const float* src = in + (size_t)e * R * C;
  u16* dst = out + (size_t)e * R * C;
  int r0 = blockIdx.y << 6, c0 = blockIdx.x << 6;
  int tr = threadIdx.x >> 4;          // 0..15
  int tc = (threadIdx.x & 15) << 2;   // 0..60
#pragma unroll
  for (int i = 0; i < 4; i++) {
    const float4 v = *(const float4*)(src + (size_t)(r0 + tr + i * 16) * C + c0 + tc);
    t[tr + i * 16][tc + 0] = v.x;
    t[tr + i * 16][tc + 1] = v.y;
    t[tr + i * 16][tc + 2] = v.z;
    t[tr + i * 16][tc + 3] = v.w;
  }
  __syncthreads();
  int oc = threadIdx.x >> 3;          // 0..31
  int rr = (threadIdx.x & 7) << 3;    // 0..56
#pragma unroll
  for (int i = 0; i < 2; i++) {
    int c = oc + (i << 5);
    u16x8 o;
#pragma unroll
    for (int j = 0; j < 8; j++) o[j] = f2bf(t[rr + j][c]);
    *(u16x8*)(dst + (size_t)(c0 + c) * R + r0 + rr) = o;
  }
}

// ---------------- router: fp32 logits, top-2, softmax; fused x->bf16 -------
__global__ __launch_bounds__(256) void router_kernel(
    const float* __restrict__ x, const float* __restrict__ Wg,
    const float* __restrict__ bg, u16* __restrict__ xbf,
    int2* __restrict__ tok_e, float2* __restrict__ tok_g,
    int* __restrict__ counts) {
  int w = threadIdx.x >> 6, lane = threadIdx.x & 63;
  int t = blockIdx.x * 4 + w;
  const float* xr = x + (size_t)t * DDIM;
  float acc[EEXP] = {0.f, 0.f, 0.f, 0.f, 0.f, 0.f, 0.f, 0.f};
#pragma unroll
  for (int j = 0; j < DDIM / 64; j++) {
    int d = j * 64 + lane;
    float xv = xr[d];
    xbf[(size_t)t * DDIM + d] = f2bf(xv);
    const float4* wv = (const float4*)(Wg + (size_t)d * EEXP);
    float4 wa = wv[0], wb = wv[1];
    acc[0] += xv * wa.x; acc[1] += xv * wa.y;
    acc[2] += xv * wa.z; acc[3] += xv * wa.w;
    acc[4] += xv * wb.x; acc[5] += xv * wb.y;
    acc[6] += xv * wb.z; acc[7] += xv * wb.w;
  }
#pragma unroll
  for (int e = 0; e < EEXP; e++) {
    float v = acc[e];
    for (int s = 32; s; s >>= 1) v += __shfl_xor(v, s);
    acc[e] = v + bg[e];
  }
  int e0 = 0; float v0 = acc[0];
#pragma unroll
  for (int e = 1; e < EEXP; e++) if (acc[e] > v0) { v0 = acc[e]; e0 = e; }
  int e1 = -1; float v1 = -3.402823466e38f;
#pragma unroll
  for (int e = 0; e < EEXP; e++)
    if (e != e0 && acc[e] > v1) { v1 = acc[e]; e1 = e; }
  float p0 = 1.f / (1.f + expf(v1 - v0));
  float p1 = 1.f - p0;
  if (lane == 0) {
    atomicAdd(&counts[e0], 1);
    atomicAdd(&counts[e1], 1);
    tok_e[t] = make_int2(e0, e1);
    tok_g[t] = make_float2(p0, p1);
  }
}

// ---------------- scan: per-expert bases (256-padded) + tile table ---------
__global__ void scan_kernel(const int* __restrict__ counts,
                            int* __restrict__ expBase,
                            int* __restrict__ tileExpert,
                            int* __restrict__ tileRow0,
                            int* __restrict__ nTiles) {
  if (threadIdx.x != 0 || blockIdx.x != 0) return;
  int base = 0, nt = 0;
  for (int e = 0; e < EEXP; e++) {
    expBase[e] = base;
    int c = counts[e];
    int tiles = (c + BM256 - 1) >> 8;
    for (int i = 0; i < tiles; i++) {
      tileExpert[nt] = e;
      tileRow0[nt] = base + (i << 8);
      nt++;
    }
    base += tiles << 8;
  }
  *nTiles = nt;
}

// ---------------- scatter: slot assignment -------------------------------
__global__ __launch_bounds__(256) void scatter_kernel(
    const int2* __restrict__ tok_e, int* __restrict__ cursor,
    const int* __restrict__ expBase, int* __restrict__ rowmap,
    int2* __restrict__ tokslot) {
  int t = blockIdx.x * 256 + threadIdx.x;
  int2 e = tok_e[t];
  int s0 = expBase[e.x] + atomicAdd(&cursor[e.x], 1);
  int s1 = expBase[e.y] + atomicAdd(&cursor[e.y], 1);
  rowmap[s0] = t;
  rowmap[s1] = t;
  tokslot[t] = make_int2(s0, s1);
}

// ---------------- grouped GEMM, 256x256 tile, counted-vmcnt 4-phase/K-tile -
// Wave (wr,wc) of 2Mx4N owns rows {wr*64..+64} u {128+wr*64..+64},
// cols {wc*32..+32} u {128+wc*32..+32}  -> quadrants need half-tiles
// incrementally: Q1(A0,B0) Q2(B1) Q3(A1) Q4(regs). Stage order per phase:
// B0(t+1),B1(t+1),A1(t+1),A0(t+2) -> every wait is vmcnt(6) (3 halves in
// flight, never drained); epilogue 4->2->0. vmcnt BEFORE s_barrier makes
// per-wave counts collective.
template <bool RELU, bool GATHER>
__global__ __launch_bounds__(512) void moe_gemm8p(
    const u16* __restrict__ A,      // [rows][K] bf16
    const u16* __restrict__ Bt,     // [E][N][K] bf16
    const float* __restrict__ bias, // [E][N]
    u16* __restrict__ C,            // [slots][N] bf16
    const int* __restrict__ rowmap,
    const int* __restrict__ tileExpert, const int* __restrict__ tileRow0,
    const int* __restrict__ nTiles, int N, int K) {
  __shared__ __align__(16) u16 As[2][2][128 * 64];   // [dbuf][half][rows*K]
  __shared__ __align__(16) u16 Bs[2][2][128 * 64];
  int ntl = N >> 8;
  int nwg = (int)gridDim.x, bid = (int)blockIdx.x;
  int swzb = (bid & 7) * (nwg >> 3) + (bid >> 3);    // XCD swizzle (nwg%8==0)
  int mtile = swzb / ntl, ntile = swzb - mtile * ntl;
  if (mtile >= *nTiles) return;
  int e = tileExpert[mtile];
  int row0 = tileRow0[mtile];
  int ncol0 = ntile << 8;
  const u16* Bm = Bt + (size_t)e * N * K;
  const float* bb = bias + (size_t)e * N;

  int tid = threadIdx.x, lane = tid & 63, wv = tid >> 6;
  int wr = wv >> 2, wc = wv & 3;
  int rlo = lane & 15, hi = lane >> 4;

  // ---- staging sources: half-tile = 128 rows x 64 k = 1024 x 16B chunks;
  // thread covers chunks {tid, tid+512}. LDS chunk (rr,kq) holds global
  // chunk (rr, kq^(rr&7))  [T2 inverse-swizzled source, linear dest].
  int rr0 = tid >> 3;                       // 0..63 (chunk2 row = rr0+64, same &7)
  int kc = (tid & 7) ^ (rr0 & 7);
  const u16 *aS[2][2], *bS[2][2];
#pragma unroll
  for (int h = 0; h < 2; h++) {
    int r0g = row0 + h * 128 + rr0, r1g = r0g + 64;
    int ar0 = GATHER ? rowmap[r0g] : r0g;
    int ar1 = GATHER ? rowmap[r1g] : r1g;
    aS[h][0] = A + (size_t)ar0 * K + kc * 8;
    aS[h][1] = A + (size_t)ar1 * K + kc * 8;
    bS[h][0] = Bm + (size_t)(ncol0 + h * 128 + rr0) * K + kc * 8;
    bS[h][1] = Bm + (size_t)(ncol0 + h * 128 + rr0 + 64) * K + kc * 8;
  }
  int d0 = tid * 8, d1 = d0 + 4096;         // u16 offsets of the 2 chunks

#define ST_A(h_, buf_, k0_) do { \
    GLD_LDS(aS[h_][0] + (k0_), &As[buf_][h_][d0]); \
    GLD_LDS(aS[h_][1] + (k0_), &As[buf_][h_][d1]); } while (0)
#define ST_B(h_, buf_, k0_) do { \
    GLD_LDS(bS[h_][0] + (k0_), &Bs[buf_][h_][d0]); \
    GLD_LDS(bS[h_][1] + (k0_), &Bs[buf_][h_][d1]); } while (0)

  // swizzled read chunk offsets (u16): frag k-chunk = (kappa*4+hi) ^ (rlo&7)
  int sw0 = ((hi + 0) ^ (rlo & 7)) * 8;
  int sw1 = ((hi + 4) ^ (rlo & 7)) * 8;

  f32x4 acc[8][4] = {};
  u16x8 af[4][2], b0f[2][2], b1f[2][2];
  int nkt = K >> 6;

  // prologue: A0(0), B0(0), B1(0), A1(0), A0(1)  (matches steady-state order)
  ST_A(0, 0, 0); ST_B(0, 0, 0); ST_B(1, 0, 0); ST_A(1, 0, 0); ST_A(0, 1, 64);
  VMC6; BARR;

  for (int t = 0; t < nkt; ++t) {
    int bc = t & 1, bn = bc ^ 1;
    int sk = (t + 1) << 6;
    const bool st1 = (t + 1 < nkt), st2 = (t + 2 < nkt);
    const u16* Ac0 = &As[bc][0][0];
    const u16* Ac1 = &As[bc][1][0];
    const u16* Bc0 = &Bs[bc][0][0];
    const u16* Bc1 = &Bs[bc][1][0];

    // ---- P1: Q(rowhalf0, colhalf0); stage B0(t+1) ----
#pragma unroll
    for (int m = 0; m < 4; m++) {
      int ro = (wr * 64 + m * 16 + rlo) * 64;
      af[m][0] = *(const u16x8*)(Ac0 + ro + sw0);
      af[m][1] = *(const u16x8*)(Ac0 + ro + sw1);
    }
#pragma unroll
    for (int n = 0; n < 2; n++) {
      int ro = (wc * 32 + n * 16 + rlo) * 64;
      b0f[n][0] = *(const u16x8*)(Bc0 + ro + sw0);
      b0f[n][1] = *(const u16x8*)(Bc0 + ro + sw1);
    }
    if (st1) { ST_B(0, bn, sk); VMC6; } else { VMC2; }
    BARR; LGK0;
    __builtin_amdgcn_s_setprio(1);
#pragma unroll
    for (int m = 0; m < 4; m++)
#pragma unroll
      for (int n = 0; n < 2; n++) {
        acc[m][n] = mf(af[m][0], b0f[n][0], acc[m][n]);
        acc[m][n] = mf(af[m][1], b0f[n][1], acc[m][n]);
      }
    __builtin_amdgcn_s_setprio(0);
    BARR;

    // ---- P2: Q(rowhalf0, colhalf1); stage B1(t+1) ----
#pragma unroll
    for (int n = 0; n < 2; n++) {
      int ro = (wc * 32 + n * 16 + rlo) * 64;
      b1f[n][0] = *(const u16x8*)(Bc1 + ro + sw0);
      b1f[n][1] = *(const u16x8*)(Bc1 + ro + sw1);
    }
    if (st1) { ST_B(1, bn, sk); VMC6; } else { VMC0; }
    BARR; LGK0;
    __builtin_amdgcn_s_setprio(1);
#pragma unroll
    for (int m = 0; m < 4; m++)
#pragma unroll
      for (int n = 0; n < 2; n++) {
        acc[m][n + 2] = mf(af[m][0], b1f[n][0], acc[m][n + 2]);
        acc[m][n + 2] = mf(af[m][1], b1f[n][1], acc[m][n + 2]);
      }
    __builtin_amdgcn_s_setprio(0);
    BARR;

    // ---- P3: Q(rowhalf1, colhalf1); stage A1(t+1) ----
#pragma unroll
    for (int m = 0; m < 4; m++) {
      int ro = (wr * 64 + m * 16 + rlo) * 64;
      af[m][0] = *(const u16x8*)(Ac1 + ro + sw0);
      af[m][1] = *(const u16x8*)(Ac1 + ro + sw1);
    }
    if (st1) { ST_A(1, bn, sk); VMC6; } else { VMC0; }
    BARR; LGK0;
    __builtin_amdgcn_s_setprio(1);
#pragma unroll
    for (int m = 0; m < 4; m++)
#pragma unroll
      for (int n = 0; n < 2; n++) {
        acc[m + 4][n + 2] = mf(af[m][0], b1f[n][0], acc[m + 4][n + 2]);
        acc[m + 4][n + 2] = mf(af[m][1], b1f[n][1], acc[m + 4][n + 2]);
      }
    __builtin_amdgcn_s_setprio(0);
    BARR;

    // ---- P4: Q(rowhalf1, colhalf0) from regs; stage A0(t+2) ----
    if (st2) { ST_A(0, bc, sk + 64); VMC6; }
    else if (st1) { VMC4; }
    else { VMC0; }
    BARR;
    __builtin_amdgcn_s_setprio(1);
#pragma unroll
    for (int m = 0; m < 4; m++)
#pragma unroll
      for (int n = 0; n < 2; n++) {
        acc[m + 4][n] = mf(af[m][0], b0f[n][0], acc[m + 4][n]);
        acc[m + 4][n] = mf(af[m][1], b0f[n][1], acc[m + 4][n]);
      }
    __builtin_amdgcn_s_setprio(0);
    BARR;
  }

  // epilogue: C/D map col=lane&15, row=(lane>>4)*4+j
#pragma unroll
  for (int rf = 0; rf < 8; rf++) {
    int rb = row0 + (rf >> 2) * 128 + wr * 64 + (rf & 3) * 16 + hi * 4;
#pragma unroll
    for (int cf = 0; cf < 4; cf++) {
      int col = ncol0 + (cf >> 1) * 128 + wc * 32 + (cf & 1) * 16 + rlo;
      float bv = bb[col];
#pragma unroll
      for (int j = 0; j < 4; j++) {
        float v = acc[rf][cf][j] + bv;
        if (RELU) v = fmaxf(v, 0.f);
        C[(size_t)(rb + j) * N + col] = f2bf(v);
      }
    }
  }
#undef ST_A
#undef ST_B
}

// ---------------- combine: out[t] = g0*Y[s0] + g1*Y[s1] --------------------
__global__ __launch_bounds__(256) void combine_kernel(
    const u16* __restrict__ Y, const int2* __restrict__ tokslot,
    const float2* __restrict__ tok_g, float* __restrict__ out) {
  int gid = blockIdx.x * 256 + threadIdx.x;  // T * 128 threads, 8 elems each
  int t = gid >> 7, seg = (gid & 127) * 8;
  int2 s = tokslot[t];
  float2 g = tok_g[t];
  u16x8 y0 = *reinterpret_cast<const u16x8*>(Y + (size_t)s.x * DDIM + seg);
  u16x8 y1 = *reinterpret_cast<const u16x8*>(Y + (size_t)s.y * DDIM + seg);
  float* op = out + (size_t)t * DDIM + seg;
#pragma unroll
  for (int i = 0; i < 8; i++)
    op[i] = g.x * bf2f(y0[i]) + g.y * bf2f(y1[i]);
}

// ---------------- launch ----------------
extern "C" void kernel_launch(void* const* d_in, const int* in_sizes, int n_in,
                              void* d_out, int out_size, void* d_ws,
                              size_t ws_size, hipStream_t stream) {
  (void)in_sizes; (void)n_in; (void)out_size; (void)ws_size;
  const float* x  = (const float*)d_in[0];
  const float* Wg = (const float*)d_in[1];
  const float* bg = (const float*)d_in[2];
  const float* W1 = (const float*)d_in[3];
  const float* b1 = (const float*)d_in[4];
  const float* W2 = (const float*)d_in[5];
  const float* b2 = (const float*)d_in[6];
  float* out = (float*)d_out;

  char* ws = (char*)d_ws;
  size_t o = 0;
  u16* W2T  = (u16*)(ws + o); o += (size_t)EEXP * HDIM * DDIM * 2;  // 67.1 MB
  u16* Hbuf = (u16*)(ws + o); o += (size_t)MAXSLOTS * HDIM * 2;     // 285.2 MB
  u16* xbf  = (u16*)(ws + o); o += (size_t)T_TOK * DDIM * 2;        // 33.6 MB
  u16* W1T  = (u16*)(ws + o); o += (size_t)EEXP * DDIM * HDIM * 2;  // 67.1 MB
  int* rowmap = (int*)(ws + o); o += (size_t)MAXSLOTS * 4;
  int2* tok_e = (int2*)(ws + o); o += (size_t)T_TOK * 8;
  float2* tok_g = (float2*)(ws + o); o += (size_t)T_TOK * 8;
  int2* tokslot = (int2*)(ws + o); o += (size_t)T_TOK * 8;
  int* counts = (int*)(ws + o); o += 8 * 4;
  int* cursor = (int*)(ws + o); o += 8 * 4;
  int* expBase = (int*)(ws + o); o += 8 * 4;
  int* nTiles = (int*)(ws + o); o += 8 * 4;
  int* tileExpert = (int*)(ws + o); o += MAXTILES * 4;
  int* tileRow0 = (int*)(ws + o); o += MAXTILES * 4;
  // Ybuf (71.3 MB) aliases xbf+W1T (100.6 MB): both dead before GEMM2 writes.
  u16* Ybuf = xbf;

  hipMemsetAsync(counts, 0, 16 * 4, stream);          // counts + cursor
  hipMemsetAsync(rowmap, 0, (size_t)MAXSLOTS * 4, stream);

  // W1 (E,D,H) -> W1T (E,H,D);  W2 (E,H,D) -> W2T (E,D,H)
  transpose_cast64<<<dim3(HDIM / 64, DDIM / 64, EEXP), 256, 0, stream>>>(W1, W1T, DDIM, HDIM);
  transpose_cast64<<<dim3(DDIM / 64, HDIM / 64, EEXP), 256, 0, stream>>>(W2, W2T, HDIM, DDIM);

  router_kernel<<<T_TOK / 4, 256, 0, stream>>>(x, Wg, bg, xbf, tok_e, tok_g, counts);
  scan_kernel<<<1, 64, 0, stream>>>(counts, expBase, tileExpert, tileRow0, nTiles);
  scatter_kernel<<<T_TOK / 256, 256, 0, stream>>>(tok_e, cursor, expBase, rowmap, tokslot);

  // GEMM1: H = relu(x[rowmap] @ W1[e] + b1[e])   N=4096, K=1024  (2176 blocks)
  moe_gemm8p<true, true><<<MAXTILES * (HDIM / 256), 512, 0, stream>>>(
      xbf, W1T, b1, Hbuf, rowmap, tileExpert, tileRow0, nTiles, HDIM, DDIM);
  // GEMM2: Y = H @ W2[e] + b2[e]                 N=1024, K=4096  (544 blocks)
  moe_gemm8p<false, false><<<MAXTILES * (DDIM / 256), 512, 0, stream>>>(
      Hbuf, W2T, b2, Ybuf, nullptr, tileExpert, tileRow0, nTiles, DDIM, HDIM);

  combine_kernel<<<(T_TOK * (DDIM / 8)) / 256, 256, 0, stream>>>(Ybuf, tokslot, tok_g, out);
}